// Round 2
// baseline (640.606 us; speedup 1.0000x reference)
//
#include <hip/hip_runtime.h>
#include <hip/hip_bf16.h>

#define EPSV 1e-5f
static const int B_ = 16, S_ = 200, D_ = 512, H_ = 8, FF_ = 2048, P_ = 10, HD_ = 64;

// ---------------------------------------------------------------------------
// Generic tiled GEMM: C[M,N] = A[M,K] @ B[N,K]^T (+ epilogue)
// EPI: 0 = optional vector bias, 1 = bias + relu,
//      2 = v*scale + posb[r*S+c]  (scores),
//      3 = bias then scatter into K-buffer / V^T-buffer (kv projection)
// cMode: 0 = Cb = C + batch*cBat ; 1 = vals-mode base (batch=(b*H+h))
// ---------------------------------------------------------------------------
template <int EPI>
__global__ __launch_bounds__(256) void gemm_bt(
    const float* __restrict__ A, long aBat,
    const float* __restrict__ Bw, long bBat,
    float* __restrict__ C, long cBat, int ldc, int cMode,
    const float* __restrict__ bias,
    const float* __restrict__ posb,
    const float* __restrict__ scalePtr,
    float* __restrict__ kOut, float* __restrict__ vtOut,
    int M, int N, int K)
{
    __shared__ float As[16][68];
    __shared__ float Bs[16][68];

    const int batch = blockIdx.z;
    const float* Ab = A + (long)batch * aBat;
    const float* Bb = Bw + (long)batch * bBat;
    float* Cb = nullptr;
    if (EPI != 3) {
        long base = (cMode == 1)
                        ? ((long)(batch >> 3) * (long)S_ * D_ + (long)(batch & 7) * HD_)
                        : (long)batch * cBat;
        Cb = C + base;
    }

    const int tid = threadIdx.x;
    const int tx = tid & 15;   // col group
    const int ty = tid >> 4;   // row group
    const int lk = tid & 15;   // k index for loads
    const int lr = tid >> 4;   // row/col index base for loads
    const int rowBase = blockIdx.y * 64;
    const int colBase = blockIdx.x * 64;

    float acc[4][4] = {};

    for (int k0 = 0; k0 < K; k0 += 16) {
        #pragma unroll
        for (int i = 0; i < 4; i++) {
            int rr = lr + i * 16;
            int r = rowBase + rr;
            int kk = k0 + lk;
            As[lk][rr] = (r < M && kk < K) ? Ab[(long)r * K + kk] : 0.f;
            int c = colBase + rr;
            Bs[lk][rr] = (c < N && kk < K) ? Bb[(long)c * K + kk] : 0.f;
        }
        __syncthreads();
        #pragma unroll
        for (int kk = 0; kk < 16; kk++) {
            const float4 av4 = *reinterpret_cast<const float4*>(&As[kk][ty * 4]);
            const float4 bv4 = *reinterpret_cast<const float4*>(&Bs[kk][tx * 4]);
            const float aa[4] = {av4.x, av4.y, av4.z, av4.w};
            const float bb[4] = {bv4.x, bv4.y, bv4.z, bv4.w};
            #pragma unroll
            for (int i = 0; i < 4; i++)
                #pragma unroll
                for (int j = 0; j < 4; j++)
                    acc[i][j] = fmaf(aa[i], bb[j], acc[i][j]);
        }
        __syncthreads();
    }

    const float scaleV = (EPI == 2) ? scalePtr[0] : 0.f;

    #pragma unroll
    for (int i = 0; i < 4; i++) {
        int r = rowBase + ty * 4 + i;
        if (r >= M) continue;
        #pragma unroll
        for (int j = 0; j < 4; j++) {
            int c = colBase + tx * 4 + j;
            if (c >= N) continue;
            float v = acc[i][j];
            if (EPI == 3) {
                v += bias[c];
                int b = r / S_, s = r - b * S_;
                int h = c >> 7, w = c & 127;
                if (w < HD_)
                    kOut[((long)(b * H_ + h) * S_ + s) * HD_ + w] = v;
                else
                    vtOut[((long)(b * H_ + h) * HD_ + (w - HD_)) * S_ + s] = v;
            } else {
                if (EPI == 1) { v += bias[c]; v = fmaxf(v, 0.f); }
                else if (EPI == 2) { v = v * scaleV + posb[(long)r * S_ + c]; }
                else if (bias) { v += bias[c]; }
                Cb[(long)r * ldc + c] = v;
            }
        }
    }
}

// posb[i][j] = sum_p pos[i][j][p]*Wpos[p] + bpos ; scale = sum(Wpos)/sqrt(HD)
__global__ void prep_posb(const float* __restrict__ pos, const float* __restrict__ Wpos,
                          const float* __restrict__ bpos, float* __restrict__ posb,
                          float* __restrict__ scale)
{
    int idx = blockIdx.x * blockDim.x + threadIdx.x;
    if (idx < S_ * S_) {
        float acc = bpos[0];
        #pragma unroll
        for (int p = 0; p < P_; p++) acc += pos[idx * P_ + p] * Wpos[p];
        posb[idx] = acc;
    }
    if (idx == 0) {
        float sw = 0.f;
        for (int p = 0; p < P_; p++) sw += Wpos[p];
        scale[0] = sw * 0.125f;  // 1/sqrt(64) folded in
    }
}

// in-place row softmax, one wave per row
__global__ __launch_bounds__(256) void softmax_rows(float* __restrict__ sc, int rows, int n)
{
    int row = blockIdx.x * 4 + (threadIdx.x >> 6);
    int lane = threadIdx.x & 63;
    if (row >= rows) return;
    float* p = sc + (long)row * n;
    float m = -1e30f;
    for (int j = lane; j < n; j += 64) m = fmaxf(m, p[j]);
    #pragma unroll
    for (int off = 32; off; off >>= 1) m = fmaxf(m, __shfl_xor(m, off));
    float s = 0.f;
    for (int j = lane; j < n; j += 64) { float e = __expf(p[j] - m); p[j] = e; s += e; }
    #pragma unroll
    for (int off = 32; off; off >>= 1) s += __shfl_xor(s, off);
    float inv = 1.f / s;
    for (int j = lane; j < n; j += 64) p[j] *= inv;
}

// out = LayerNorm(a + b) * g + beta ; one wave per row of 512
__global__ __launch_bounds__(256) void add_ln(
    const float* __restrict__ a, const float* __restrict__ b,
    const float* __restrict__ g, const float* __restrict__ beta,
    float* __restrict__ out, int rows)
{
    int row = blockIdx.x * 4 + (threadIdx.x >> 6);
    int lane = threadIdx.x & 63;
    if (row >= rows) return;
    long base = (long)row * D_;
    float v[8];
    float sum = 0.f;
    #pragma unroll
    for (int i = 0; i < 8; i++) {
        int c = lane + i * 64;
        v[i] = a[base + c] + b[base + c];
        sum += v[i];
    }
    #pragma unroll
    for (int off = 32; off; off >>= 1) sum += __shfl_xor(sum, off);
    float mean = sum * (1.f / 512.f);
    float var = 0.f;
    #pragma unroll
    for (int i = 0; i < 8; i++) { float d = v[i] - mean; var += d * d; }
    #pragma unroll
    for (int off = 32; off; off >>= 1) var += __shfl_xor(var, off);
    float rstd = rsqrtf(var * (1.f / 512.f) + EPSV);
    #pragma unroll
    for (int i = 0; i < 8; i++) {
        int c = lane + i * 64;
        out[base + c] = (v[i] - mean) * rstd * g[c] + beta[c];
    }
}

extern "C" void kernel_launch(void* const* d_in, const int* in_sizes, int n_in,
                              void* d_out, int out_size, void* d_ws, size_t ws_size,
                              hipStream_t stream)
{
    const float* x    = (const float*)d_in[0];
    const float* pos  = (const float*)d_in[1];
    const float* Wkv  = (const float*)d_in[2];
    const float* bkv  = (const float*)d_in[3];
    const float* Wo   = (const float*)d_in[4];
    const float* bo   = (const float*)d_in[5];
    const float* Wpos = (const float*)d_in[6];
    const float* bpos = (const float*)d_in[7];
    const float* W1   = (const float*)d_in[8];
    const float* b1   = (const float*)d_in[9];
    const float* W2   = (const float*)d_in[10];
    const float* b2   = (const float*)d_in[11];
    const float* g1   = (const float*)d_in[12];
    const float* be1  = (const float*)d_in[13];
    const float* g2   = (const float*)d_in[14];
    const float* be2  = (const float*)d_in[15];
    float* out = (float*)d_out;

    float* ws = (float*)d_ws;
    long off = 0;
    float* Kb     = ws + off; off += (long)B_ * H_ * S_ * HD_;  // 1,638,400
    float* Vt     = ws + off; off += (long)B_ * H_ * HD_ * S_;  // 1,638,400
    float* posb   = ws + off; off += S_ * S_;                   // 40,000
    float* scal   = ws + off; off += 64;
    float* scores = ws + off; off += (long)B_ * H_ * S_ * S_;   // 5,120,000
    float* vals   = ws + off; off += (long)B_ * S_ * D_;
    float* obuf   = ws + off; off += (long)B_ * S_ * D_;
    float* hbuf   = ws + off; off += (long)B_ * S_ * D_;
    float* tbuf   = ws + off; off += (long)B_ * S_ * FF_;       // 6,553,600
    float* fbuf   = ws + off; off += (long)B_ * S_ * D_;

    const int M = B_ * S_;  // 3200

    // 1) positional bias + scale
    prep_posb<<<(S_ * S_ + 255) / 256, 256, 0, stream>>>(pos, Wpos, bpos, posb, scal);

    // 2) kv = x @ Wkv^T + bkv -> scatter K [BH,S,64], V^T [BH,64,S]
    {
        dim3 g((2 * D_ + 63) / 64, (M + 63) / 64, 1);
        gemm_bt<3><<<g, 256, 0, stream>>>(
            x, 0, Wkv, 0, nullptr, 0, 0, 0, bkv, nullptr, nullptr, Kb, Vt, M, 2 * D_, D_);
    }
    // 3) scores = (K @ K^T) * scale + posb  (batched over B*H)
    {
        dim3 g((S_ + 63) / 64, (S_ + 63) / 64, B_ * H_);
        gemm_bt<2><<<g, 256, 0, stream>>>(
            Kb, (long)S_ * HD_, Kb, (long)S_ * HD_,
            scores, (long)S_ * S_, S_, 0, nullptr, posb, scal, nullptr, nullptr, S_, S_, HD_);
    }
    // 4) softmax rows (in place)
    softmax_rows<<<(B_ * H_ * S_ + 3) / 4, 256, 0, stream>>>(scores, B_ * H_ * S_, S_);

    // 5) vals = a @ V  (B operand is V^T stored [64,S]) -> written as (B,S,D)
    {
        dim3 g((HD_ + 63) / 64, (S_ + 63) / 64, B_ * H_);
        gemm_bt<0><<<g, 256, 0, stream>>>(
            scores, (long)S_ * S_, Vt, (long)HD_ * S_,
            vals, 0, D_, 1, nullptr, nullptr, nullptr, nullptr, nullptr, S_, HD_, S_);
    }
    // 6) o = vals @ Wo^T + bo
    {
        dim3 g((D_ + 63) / 64, (M + 63) / 64, 1);
        gemm_bt<0><<<g, 256, 0, stream>>>(
            vals, 0, Wo, 0, obuf, 0, D_, 0, bo, nullptr, nullptr, nullptr, nullptr, M, D_, D_);
    }
    // 7) h = LN(x + o)
    add_ln<<<(M + 3) / 4, 256, 0, stream>>>(x, obuf, g1, be1, hbuf, M);

    // 8) t = relu(h @ W1^T + b1)
    {
        dim3 g((FF_ + 63) / 64, (M + 63) / 64, 1);
        gemm_bt<1><<<g, 256, 0, stream>>>(
            hbuf, 0, W1, 0, tbuf, 0, FF_, 0, b1, nullptr, nullptr, nullptr, nullptr, M, FF_, D_);
    }
    // 9) f = t @ W2^T + b2
    {
        dim3 g((D_ + 63) / 64, (M + 63) / 64, 1);
        gemm_bt<0><<<g, 256, 0, stream>>>(
            tbuf, 0, W2, 0, fbuf, 0, D_, 0, b2, nullptr, nullptr, nullptr, nullptr, M, D_, FF_);
    }
    // 10) out = LN(h + f) -> f32
    add_ln<<<(M + 3) / 4, 256, 0, stream>>>(hbuf, fbuf, g2, be2, out, M);
}

// Round 3
// 187.155 us; speedup vs baseline: 3.4229x; 3.4229x over previous
//
#include <hip/hip_runtime.h>
#include <hip/hip_bf16.h>

#define EPSV 1e-5f
static const int B_ = 16, S_ = 200, D_ = 512, H_ = 8, FF_ = 2048, P_ = 10, HD_ = 64;

typedef __bf16 bf16_t;
typedef __attribute__((ext_vector_type(8))) __bf16 bf16x8;
typedef __attribute__((ext_vector_type(4))) __bf16 bf16x4;
typedef __attribute__((ext_vector_type(4))) float f32x4;

__device__ __forceinline__ void gload16(const void* g, void* l) {
    __builtin_amdgcn_global_load_lds(
        (const __attribute__((address_space(1))) void*)g,
        (__attribute__((address_space(3))) void*)l, 16, 0, 0);
}

// ---------------------------------------------------------------------------
// bf16 MFMA GEMM: C[M,N] = A[M,K] @ B[N,K]^T  (A,B bf16 row-major, K mult of 64)
// 256 threads, 4 waves. BM x BN tile; each wave WROWS x WCOLS.
// EPI: 0 = +bias -> f32 ; 1 = +bias,relu -> bf16 ; 2 = *scale+posb -> f32 ;
//      3 = +bias, scatter K/Vt bf16 ; 4 = vals-mode -> bf16 (batch=(b*H+h))
// ---------------------------------------------------------------------------
template <int BM, int BN, int WROWS, int WCOLS, int EPI>
__global__ __launch_bounds__(256) void mfma_gemm(
    const bf16_t* __restrict__ A, long aBat,
    const bf16_t* __restrict__ Bw, long bBat,
    float* __restrict__ Cf, bf16_t* __restrict__ Cb, long cBat, int ldc,
    const float* __restrict__ bias,
    const float* __restrict__ posb, const float* __restrict__ scalePtr,
    bf16_t* __restrict__ kOut, bf16_t* __restrict__ vtOut,
    int M, int N, int K)
{
    constexpr int MR = WROWS / 16, NR = WCOLS / 16;
    constexpr int NWC = BN / WCOLS;  // waves along cols

    __shared__ bf16_t Asm[BM * 64];
    __shared__ bf16_t Bsm[BN * 64];

    const int wv = threadIdx.x >> 6;
    const int ln = threadIdx.x & 63;
    const int batch = blockIdx.z;
    const bf16_t* Ab = A + (long)batch * aBat;
    const bf16_t* Bb = Bw + (long)batch * bBat;
    const int rowBase = blockIdx.y * BM;
    const int colBase = blockIdx.x * BN;
    const int wr = (wv / NWC) * WROWS;
    const int wc = (wv % NWC) * WCOLS;

    const int lr8 = ln >> 3;        // 0..7  (row within 8-row group)
    const int lc = (ln & 7) * 8;    // k-chunk element offset

    f32x4 acc[MR][NR] = {};

    for (int k0 = 0; k0 < K; k0 += 64) {
        // stage A tile [BM][64] (linear, lane-contiguous 16B chunks)
        #pragma unroll
        for (int i = 0; i < BM / 32; i++) {
            int row = i * 32 + wv * 8 + lr8;
            int gr = rowBase + row; gr = (gr < M) ? gr : (M - 1);
            gload16(Ab + (long)gr * K + k0 + lc, &Asm[(i * 32 + wv * 8) * 64]);
        }
        #pragma unroll
        for (int i = 0; i < BN / 32; i++) {
            int col = i * 32 + wv * 8 + lr8;
            int gc = colBase + col; gc = (gc < N) ? gc : (N - 1);
            gload16(Bb + (long)gc * K + k0 + lc, &Bsm[(i * 32 + wv * 8) * 64]);
        }
        __syncthreads();  // drains vmcnt -> LDS valid

        #pragma unroll
        for (int kk = 0; kk < 2; kk++) {
            bf16x8 af[MR], bfr[NR];
            #pragma unroll
            for (int m = 0; m < MR; m++)
                af[m] = *reinterpret_cast<const bf16x8*>(
                    &Asm[(wr + m * 16 + (ln & 15)) * 64 + kk * 32 + (ln >> 4) * 8]);
            #pragma unroll
            for (int n = 0; n < NR; n++)
                bfr[n] = *reinterpret_cast<const bf16x8*>(
                    &Bsm[(wc + n * 16 + (ln & 15)) * 64 + kk * 32 + (ln >> 4) * 8]);
            #pragma unroll
            for (int m = 0; m < MR; m++)
                #pragma unroll
                for (int n = 0; n < NR; n++)
                    acc[m][n] = __builtin_amdgcn_mfma_f32_16x16x32_bf16(
                        af[m], bfr[n], acc[m][n], 0, 0, 0);
        }
        __syncthreads();  // reads done before next stage overwrites
    }

    const float scaleV = (EPI == 2) ? scalePtr[0] : 0.f;
    long cbase;
    if constexpr (EPI == 4)
        cbase = (long)(batch >> 3) * (S_ * D_) + (long)(batch & 7) * HD_;
    else
        cbase = (long)batch * cBat;

    #pragma unroll
    for (int m = 0; m < MR; m++) {
        #pragma unroll
        for (int n = 0; n < NR; n++) {
            #pragma unroll
            for (int r = 0; r < 4; r++) {
                int row = rowBase + wr + m * 16 + (ln >> 4) * 4 + r;
                int col = colBase + wc + n * 16 + (ln & 15);
                if (row >= M || col >= N) continue;
                float v = acc[m][n][r];
                if constexpr (EPI == 3) {
                    v += bias[col];
                    int b = row / S_, s = row - b * S_;
                    int h = col >> 7, w = col & 127;
                    if (w < HD_)
                        kOut[((long)(b * H_ + h) * S_ + s) * HD_ + w] = (bf16_t)v;
                    else
                        vtOut[((long)(b * H_ + h) * HD_ + (w - HD_)) * 256 + s] = (bf16_t)v;
                } else if constexpr (EPI == 2) {
                    Cf[cbase + (long)row * ldc + col] = v * scaleV + posb[row * S_ + col];
                } else if constexpr (EPI == 1) {
                    v += bias[col];
                    v = fmaxf(v, 0.f);
                    Cb[cbase + (long)row * ldc + col] = (bf16_t)v;
                } else if constexpr (EPI == 4) {
                    Cb[cbase + (long)row * ldc + col] = (bf16_t)v;
                } else {
                    v += bias[col];
                    Cf[cbase + (long)row * ldc + col] = v;
                }
            }
        }
    }
}

// fused f32 -> bf16 conversion of x, Wkv, Wo, W1, W2 into one contiguous region
__global__ __launch_bounds__(256) void convert_all(
    const float* __restrict__ x, const float* __restrict__ Wkv,
    const float* __restrict__ Wo, const float* __restrict__ W1,
    const float* __restrict__ W2, bf16_t* __restrict__ dst)
{
    const int tot = 1130496;  // 4,521,984 / 4
    for (int i = blockIdx.x * blockDim.x + threadIdx.x; i < tot;
         i += gridDim.x * blockDim.x) {
        long e = (long)i * 4;
        const float* s; long off;
        if (e < 1638400)      { s = x;   off = e; }
        else if (e < 2162688) { s = Wkv; off = e - 1638400; }
        else if (e < 2424832) { s = Wo;  off = e - 2162688; }
        else if (e < 3473408) { s = W1;  off = e - 2424832; }
        else                  { s = W2;  off = e - 3473408; }
        float4 v = *reinterpret_cast<const float4*>(s + off);
        bf16x4 o = {(bf16_t)v.x, (bf16_t)v.y, (bf16_t)v.z, (bf16_t)v.w};
        *reinterpret_cast<bf16x4*>(dst + e) = o;
    }
}

__global__ __launch_bounds__(256) void zero_f4(float4* __restrict__ p, int n4)
{
    int i = blockIdx.x * blockDim.x + threadIdx.x;
    if (i < n4) p[i] = make_float4(0.f, 0.f, 0.f, 0.f);
}

// posb[i][j] = sum_p pos[i][j][p]*Wpos[p] + bpos ; scale = sum(Wpos)/sqrt(HD)
__global__ void prep_posb(const float* __restrict__ pos, const float* __restrict__ Wpos,
                          const float* __restrict__ bpos, float* __restrict__ posb,
                          float* __restrict__ scale)
{
    int idx = blockIdx.x * blockDim.x + threadIdx.x;
    if (idx < S_ * S_) {
        float acc = bpos[0];
        #pragma unroll
        for (int p = 0; p < P_; p++) acc += pos[idx * P_ + p] * Wpos[p];
        posb[idx] = acc;
    }
    if (idx == 0) {
        float sw = 0.f;
        for (int p = 0; p < P_; p++) sw += Wpos[p];
        scale[0] = sw * 0.125f;
    }
}

// softmax over 200 cols (f32 in, stride 208) -> bf16 P (stride 256, zero-padded)
__global__ __launch_bounds__(256) void softmax_p(
    const float* __restrict__ sc, bf16_t* __restrict__ P)
{
    int row = blockIdx.x * 4 + (threadIdx.x >> 6);
    if (row >= 25600) return;
    int lane = threadIdx.x & 63;
    const float* pr = sc + (long)row * 208;
    bf16_t* po = P + (long)row * 256;
    float v[4], e[4];
    float m = -1e30f;
    #pragma unroll
    for (int i = 0; i < 4; i++) {
        int j = lane + i * 64;
        v[i] = (j < S_) ? pr[j] : -1e30f;
        m = fmaxf(m, v[i]);
    }
    #pragma unroll
    for (int off = 32; off; off >>= 1) m = fmaxf(m, __shfl_xor(m, off));
    float s = 0.f;
    #pragma unroll
    for (int i = 0; i < 4; i++) {
        int j = lane + i * 64;
        e[i] = (j < S_) ? __expf(v[i] - m) : 0.f;
        s += e[i];
    }
    #pragma unroll
    for (int off = 32; off; off >>= 1) s += __shfl_xor(s, off);
    float inv = 1.f / s;
    #pragma unroll
    for (int i = 0; i < 4; i++) po[lane + i * 64] = (bf16_t)(e[i] * inv);
}

// out = LayerNorm(a + b); writes f32 (outf) and optionally bf16 (outb)
__global__ __launch_bounds__(256) void add_ln2(
    const float* __restrict__ a, const float* __restrict__ b,
    const float* __restrict__ g, const float* __restrict__ beta,
    float* __restrict__ outf, bf16_t* __restrict__ outb, int rows)
{
    int row = blockIdx.x * 4 + (threadIdx.x >> 6);
    int lane = threadIdx.x & 63;
    if (row >= rows) return;
    long base = (long)row * D_;
    float v[8];
    float sum = 0.f;
    #pragma unroll
    for (int i = 0; i < 8; i++) {
        int c = lane + i * 64;
        v[i] = a[base + c] + b[base + c];
        sum += v[i];
    }
    #pragma unroll
    for (int off = 32; off; off >>= 1) sum += __shfl_xor(sum, off);
    float mean = sum * (1.f / 512.f);
    float var = 0.f;
    #pragma unroll
    for (int i = 0; i < 8; i++) { float d = v[i] - mean; var += d * d; }
    #pragma unroll
    for (int off = 32; off; off >>= 1) var += __shfl_xor(var, off);
    float rstd = rsqrtf(var * (1.f / 512.f) + EPSV);
    #pragma unroll
    for (int i = 0; i < 8; i++) {
        int c = lane + i * 64;
        float o = (v[i] - mean) * rstd * g[c] + beta[c];
        outf[base + c] = o;
        if (outb) outb[base + c] = (bf16_t)o;
    }
}

extern "C" void kernel_launch(void* const* d_in, const int* in_sizes, int n_in,
                              void* d_out, int out_size, void* d_ws, size_t ws_size,
                              hipStream_t stream)
{
    const float* x    = (const float*)d_in[0];
    const float* pos  = (const float*)d_in[1];
    const float* Wkv  = (const float*)d_in[2];
    const float* bkv  = (const float*)d_in[3];
    const float* Wo   = (const float*)d_in[4];
    const float* bo   = (const float*)d_in[5];
    const float* Wpos = (const float*)d_in[6];
    const float* bpos = (const float*)d_in[7];
    const float* W1   = (const float*)d_in[8];
    const float* b1   = (const float*)d_in[9];
    const float* W2   = (const float*)d_in[10];
    const float* b2   = (const float*)d_in[11];
    const float* g1   = (const float*)d_in[12];
    const float* be1  = (const float*)d_in[13];
    const float* g2   = (const float*)d_in[14];
    const float* be2  = (const float*)d_in[15];
    float* out = (float*)d_out;

    char* w = (char*)d_ws;
    // bf16 conversion region (contiguous: x, Wkv, Wo, W1, W2)
    bf16_t* xb   = (bf16_t*)(w + 0);
    bf16_t* Wkvb = (bf16_t*)(w + 3276800);
    bf16_t* Wob  = (bf16_t*)(w + 4325376);
    bf16_t* W1b  = (bf16_t*)(w + 4849664);
    bf16_t* W2b  = (bf16_t*)(w + 6946816);
    bf16_t* Kb   = (bf16_t*)(w + 9043968);    // [128][200][64]
    bf16_t* Vt   = (bf16_t*)(w + 12320768);   // [128][64][256] zero-padded
    float*  posb = (float*)(w + 16515072);    // [200][200]
    float*  scal = (float*)(w + 16675328);
    bf16_t* vals = (bf16_t*)(w + 16675584);   // [3200][512]
    float*  hf   = (float*)(w + 19952384);    // [3200][512] f32
    bf16_t* hb   = (bf16_t*)(w + 26505984);   // [3200][512] bf16
    char*   R    = w + 29782784;              // aliased region
    float*  scores = (float*)(R);             // [25600][208] f32
    bf16_t* P    = (bf16_t*)(R + 21299200);   // [25600][256] bf16, zero-padded
    float*  obuf = (float*)(R);               // [3200][512] f32   (after P dead)
    bf16_t* tb   = (bf16_t*)(R + 6553600);    // [3200][2048] bf16
    float*  fbuf = (float*)(R + 19660800);    // [3200][512] f32

    const int M = B_ * S_;  // 3200

    // 1) f32 -> bf16 converts
    convert_all<<<2048, 256, 0, stream>>>(x, Wkv, Wo, W1, W2, xb);
    // 2) zero Vt (for K-padding of the P@V GEMM)
    zero_f4<<<1024, 256, 0, stream>>>((float4*)Vt, 262144);
    // 3) positional bias + scale
    prep_posb<<<(S_ * S_ + 255) / 256, 256, 0, stream>>>(pos, Wpos, bpos, posb, scal);

    // 4) kv = x @ Wkv^T + bkv -> scatter K bf16 [BH,200,64], V^T bf16 [BH,64,256]
    mfma_gemm<128, 128, 64, 64, 3><<<dim3(8, 25, 1), 256, 0, stream>>>(
        xb, 0, Wkvb, 0, nullptr, nullptr, 0, 0, bkv, nullptr, nullptr, Kb, Vt,
        M, 2 * D_, D_);

    // 5) scores = (K @ K^T)*scale + posb -> f32 [BH][200][208]
    mfma_gemm<128, 128, 64, 64, 2><<<dim3(2, 2, 128), 256, 0, stream>>>(
        Kb, (long)S_ * HD_, Kb, (long)S_ * HD_, scores, nullptr, (long)S_ * 208, 208,
        nullptr, posb, scal, nullptr, nullptr, S_, S_, HD_);

    // 6) softmax rows -> bf16 P [BH][200][256] (zero-padded)
    softmax_p<<<6400, 256, 0, stream>>>(scores, P);

    // 7) vals = P @ V  (B operand = V^T [64][256]) -> bf16 vals (B,S,D)
    mfma_gemm<128, 64, 32, 64, 4><<<dim3(1, 2, 128), 256, 0, stream>>>(
        P, (long)S_ * 256, Vt, (long)HD_ * 256, nullptr, vals, 0, D_,
        nullptr, nullptr, nullptr, nullptr, nullptr, S_, HD_, 256);

    // 8) o = vals @ Wo^T + bo -> f32 obuf
    mfma_gemm<128, 128, 64, 64, 0><<<dim3(4, 25, 1), 256, 0, stream>>>(
        vals, 0, Wob, 0, obuf, nullptr, 0, D_, bo, nullptr, nullptr, nullptr, nullptr,
        M, D_, D_);

    // 9) h = LN(x + o) -> hf (f32) + hb (bf16)
    add_ln2<<<(M + 3) / 4, 256, 0, stream>>>(x, obuf, g1, be1, hf, hb, M);

    // 10) t = relu(h @ W1^T + b1) -> bf16 tb
    mfma_gemm<128, 128, 64, 64, 1><<<dim3(16, 25, 1), 256, 0, stream>>>(
        hb, 0, W1b, 0, nullptr, tb, 0, FF_, b1, nullptr, nullptr, nullptr, nullptr,
        M, FF_, D_);

    // 11) f = t @ W2^T + b2 -> f32 fbuf
    mfma_gemm<128, 128, 64, 64, 0><<<dim3(4, 25, 1), 256, 0, stream>>>(
        tb, 0, W2b, 0, fbuf, nullptr, 0, D_, b2, nullptr, nullptr, nullptr, nullptr,
        M, D_, FF_);

    // 12) out = LN(h + f) -> f32
    add_ln2<<<(M + 3) / 4, 256, 0, stream>>>(hf, fbuf, g2, be2, out, nullptr, M);
}

// Round 4
// 129.617 us; speedup vs baseline: 4.9423x; 1.4439x over previous
//
#include <hip/hip_runtime.h>
#include <hip/hip_bf16.h>

#define EPSV 1e-5f
static const int B_ = 16, S_ = 200, D_ = 512, H_ = 8, FF_ = 2048, P_ = 10, HD_ = 64;

typedef __bf16 bf16_t;
typedef __attribute__((ext_vector_type(8))) __bf16 bf16x8;
typedef __attribute__((ext_vector_type(4))) __bf16 bf16x4;
typedef __attribute__((ext_vector_type(4))) float f32x4;

__device__ __forceinline__ void gload16(const void* g, void* l) {
    __builtin_amdgcn_global_load_lds(
        (const __attribute__((address_space(1))) void*)g,
        (__attribute__((address_space(3))) void*)l, 16, 0, 0);
}

// ---------------------------------------------------------------------------
// bf16 MFMA GEMM: C[M,N] = A[M,K] @ B[N,K]^T, 256 thr / 4 waves, BK=64.
// EPI: 1 = +bias,relu -> bf16 ; 2 = *scale+posb -> f32 ;
//      3 = +bias, scatter K/Vt bf16 ; 4 = vals-mode -> bf16 (batch=(b*H+h)) ;
//      5 = split-K partial -> f32 (no bias)
// NSPLIT: blockIdx.z = batch*NSPLIT + split ; split covers K/NSPLIT.
// ---------------------------------------------------------------------------
template <int BM, int BN, int WROWS, int WCOLS, int EPI, int NSPLIT>
__global__ __launch_bounds__(256) void mfma_gemm(
    const bf16_t* __restrict__ A, long aBat,
    const bf16_t* __restrict__ Bw, long bBat,
    float* __restrict__ Cf, bf16_t* __restrict__ Cb, long cBat, int ldc,
    const float* __restrict__ bias,
    const float* __restrict__ posb, const float* __restrict__ scalePtr,
    bf16_t* __restrict__ kOut, bf16_t* __restrict__ vtOut,
    int M, int N, int K)
{
    constexpr int MR = WROWS / 16, NR = WCOLS / 16;
    constexpr int NWC = BN / WCOLS;  // waves along cols
    static_assert((4 / NWC) * WROWS == BM, "wave tiling must cover BM");
    static_assert(NWC * WCOLS == BN, "wave tiling must cover BN");

    __shared__ bf16_t Asm[BM * 64];
    __shared__ bf16_t Bsm[BN * 64];

    const int wv = threadIdx.x >> 6;
    const int ln = threadIdx.x & 63;
    const int batch = blockIdx.z / NSPLIT;
    const int split = blockIdx.z % NSPLIT;
    const bf16_t* Ab = A + (long)batch * aBat;
    const bf16_t* Bb = Bw + (long)batch * bBat;
    const int rowBase = blockIdx.y * BM;
    const int colBase = blockIdx.x * BN;
    const int wr = (wv / NWC) * WROWS;
    const int wc = (wv % NWC) * WCOLS;

    const int lr8 = ln >> 3;      // 0..7
    const int lc = (ln & 7) * 8;  // k element offset

    f32x4 acc[MR][NR] = {};

    const int kBeg = split * (K / NSPLIT);
    const int kEnd = kBeg + K / NSPLIT;

    for (int k0 = kBeg; k0 < kEnd; k0 += 64) {
        #pragma unroll
        for (int i = 0; i < BM / 32; i++) {
            int row = i * 32 + wv * 8 + lr8;
            int gr = rowBase + row; gr = (gr < M) ? gr : (M - 1);
            gload16(Ab + (long)gr * K + k0 + lc, &Asm[(i * 32 + wv * 8) * 64]);
        }
        #pragma unroll
        for (int i = 0; i < BN / 32; i++) {
            int col = i * 32 + wv * 8 + lr8;
            int gc = colBase + col; gc = (gc < N) ? gc : (N - 1);
            gload16(Bb + (long)gc * K + k0 + lc, &Bsm[(i * 32 + wv * 8) * 64]);
        }
        __syncthreads();  // drains vmcnt -> LDS valid

        #pragma unroll
        for (int kk = 0; kk < 2; kk++) {
            bf16x8 af[MR], bfr[NR];
            #pragma unroll
            for (int m = 0; m < MR; m++)
                af[m] = *reinterpret_cast<const bf16x8*>(
                    &Asm[(wr + m * 16 + (ln & 15)) * 64 + kk * 32 + (ln >> 4) * 8]);
            #pragma unroll
            for (int n = 0; n < NR; n++)
                bfr[n] = *reinterpret_cast<const bf16x8*>(
                    &Bsm[(wc + n * 16 + (ln & 15)) * 64 + kk * 32 + (ln >> 4) * 8]);
            #pragma unroll
            for (int m = 0; m < MR; m++)
                #pragma unroll
                for (int n = 0; n < NR; n++)
                    acc[m][n] = __builtin_amdgcn_mfma_f32_16x16x32_bf16(
                        af[m], bfr[n], acc[m][n], 0, 0, 0);
        }
        __syncthreads();
    }

    const float scaleV = (EPI == 2) ? scalePtr[0] : 0.f;
    long cbase;
    if constexpr (EPI == 4)
        cbase = (long)(batch >> 3) * (S_ * D_) + (long)(batch & 7) * HD_;
    else if constexpr (EPI == 5)
        cbase = (long)split * cBat;
    else
        cbase = (long)batch * cBat;

    #pragma unroll
    for (int m = 0; m < MR; m++) {
        #pragma unroll
        for (int n = 0; n < NR; n++) {
            #pragma unroll
            for (int r = 0; r < 4; r++) {
                int row = rowBase + wr + m * 16 + (ln >> 4) * 4 + r;
                int col = colBase + wc + n * 16 + (ln & 15);
                if (row >= M || col >= N) continue;
                float v = acc[m][n][r];
                if constexpr (EPI == 3) {
                    v += bias[col];
                    int b = row / S_, s = row - b * S_;
                    int h = col >> 7, w = col & 127;
                    if (w < HD_)
                        kOut[((long)(b * H_ + h) * S_ + s) * HD_ + w] = (bf16_t)v;
                    else
                        vtOut[((long)(b * H_ + h) * HD_ + (w - HD_)) * 256 + s] = (bf16_t)v;
                } else if constexpr (EPI == 2) {
                    Cf[cbase + (long)row * ldc + col] = v * scaleV + posb[row * S_ + col];
                } else if constexpr (EPI == 1) {
                    v += bias[col];
                    v = fmaxf(v, 0.f);
                    Cb[cbase + (long)row * ldc + col] = (bf16_t)v;
                } else if constexpr (EPI == 4) {
                    Cb[cbase + (long)row * ldc + col] = (bf16_t)v;
                } else {  // 5
                    Cf[cbase + (long)row * ldc + col] = v;
                }
            }
        }
    }
}

// fused f32 -> bf16 conversion of x, Wkv, Wo, W1, W2 into one contiguous region
__global__ __launch_bounds__(256) void convert_all(
    const float* __restrict__ x, const float* __restrict__ Wkv,
    const float* __restrict__ Wo, const float* __restrict__ W1,
    const float* __restrict__ W2, bf16_t* __restrict__ dst)
{
    const int tot = 1130496;  // 4,521,984 / 4
    for (int i = blockIdx.x * blockDim.x + threadIdx.x; i < tot;
         i += gridDim.x * blockDim.x) {
        long e = (long)i * 4;
        const float* s; long off;
        if (e < 1638400)      { s = x;   off = e; }
        else if (e < 2162688) { s = Wkv; off = e - 1638400; }
        else if (e < 2424832) { s = Wo;  off = e - 2162688; }
        else if (e < 3473408) { s = W1;  off = e - 2424832; }
        else                  { s = W2;  off = e - 3473408; }
        float4 v = *reinterpret_cast<const float4*>(s + off);
        bf16x4 o = {(bf16_t)v.x, (bf16_t)v.y, (bf16_t)v.z, (bf16_t)v.w};
        *reinterpret_cast<bf16x4*>(dst + e) = o;
    }
}

__global__ __launch_bounds__(256) void zero_f4(float4* __restrict__ p, int n4)
{
    int i = blockIdx.x * blockDim.x + threadIdx.x;
    if (i < n4) p[i] = make_float4(0.f, 0.f, 0.f, 0.f);
}

// posb[i][j] = sum_p pos[i][j][p]*Wpos[p] + bpos ; scale = sum(Wpos)/sqrt(HD)
__global__ void prep_posb(const float* __restrict__ pos, const float* __restrict__ Wpos,
                          const float* __restrict__ bpos, float* __restrict__ posb,
                          float* __restrict__ scale)
{
    int idx = blockIdx.x * blockDim.x + threadIdx.x;
    if (idx < S_ * S_) {
        float acc = bpos[0];
        #pragma unroll
        for (int p = 0; p < P_; p++) acc += pos[idx * P_ + p] * Wpos[p];
        posb[idx] = acc;
    }
    if (idx == 0) {
        float sw = 0.f;
        for (int p = 0; p < P_; p++) sw += Wpos[p];
        scale[0] = sw * 0.125f;
    }
}

// softmax over 200 cols (f32 in, stride 208) -> bf16 P (stride 256, zero-padded)
__global__ __launch_bounds__(256) void softmax_p(
    const float* __restrict__ sc, bf16_t* __restrict__ P)
{
    int row = blockIdx.x * 4 + (threadIdx.x >> 6);
    if (row >= 25600) return;
    int lane = threadIdx.x & 63;
    const float* pr = sc + (long)row * 208;
    bf16_t* po = P + (long)row * 256;
    float v[4], e[4];
    float m = -1e30f;
    #pragma unroll
    for (int i = 0; i < 4; i++) {
        int j = lane + i * 64;
        v[i] = (j < S_) ? pr[j] : -1e30f;
        m = fmaxf(m, v[i]);
    }
    #pragma unroll
    for (int off = 32; off; off >>= 1) m = fmaxf(m, __shfl_xor(m, off));
    float s = 0.f;
    #pragma unroll
    for (int i = 0; i < 4; i++) {
        int j = lane + i * 64;
        e[i] = (j < S_) ? __expf(v[i] - m) : 0.f;
        s += e[i];
    }
    #pragma unroll
    for (int off = 32; off; off >>= 1) s += __shfl_xor(s, off);
    float inv = 1.f / s;
    #pragma unroll
    for (int i = 0; i < 4; i++) po[lane + i * 64] = (bf16_t)(e[i] * inv);
}

// out = LayerNorm(a + sum_p parts[p] + bias); writes f32 outf, optional bf16 outb
template <int NPART>
__global__ __launch_bounds__(256) void add_ln_p(
    const float* __restrict__ a, const float* __restrict__ parts, long partStride,
    const float* __restrict__ bias,
    const float* __restrict__ g, const float* __restrict__ beta,
    float* __restrict__ outf, bf16_t* __restrict__ outb, int rows)
{
    int row = blockIdx.x * 4 + (threadIdx.x >> 6);
    int lane = threadIdx.x & 63;
    if (row >= rows) return;
    long base = (long)row * D_;
    float v[8];
    float sum = 0.f;
    #pragma unroll
    for (int i = 0; i < 8; i++) {
        int c = lane + i * 64;
        float t = a[base + c] + bias[c];
        #pragma unroll
        for (int p = 0; p < NPART; p++) t += parts[p * partStride + base + c];
        v[i] = t;
        sum += t;
    }
    #pragma unroll
    for (int off = 32; off; off >>= 1) sum += __shfl_xor(sum, off);
    float mean = sum * (1.f / 512.f);
    float var = 0.f;
    #pragma unroll
    for (int i = 0; i < 8; i++) { float d = v[i] - mean; var += d * d; }
    #pragma unroll
    for (int off = 32; off; off >>= 1) var += __shfl_xor(var, off);
    float rstd = rsqrtf(var * (1.f / 512.f) + EPSV);
    #pragma unroll
    for (int i = 0; i < 8; i++) {
        int c = lane + i * 64;
        float o = (v[i] - mean) * rstd * g[c] + beta[c];
        outf[base + c] = o;
        if (outb) outb[base + c] = (bf16_t)o;
    }
}

extern "C" void kernel_launch(void* const* d_in, const int* in_sizes, int n_in,
                              void* d_out, int out_size, void* d_ws, size_t ws_size,
                              hipStream_t stream)
{
    const float* x    = (const float*)d_in[0];
    const float* pos  = (const float*)d_in[1];
    const float* Wkv  = (const float*)d_in[2];
    const float* bkv  = (const float*)d_in[3];
    const float* Wo   = (const float*)d_in[4];
    const float* bo   = (const float*)d_in[5];
    const float* Wpos = (const float*)d_in[6];
    const float* bpos = (const float*)d_in[7];
    const float* W1   = (const float*)d_in[8];
    const float* b1   = (const float*)d_in[9];
    const float* W2   = (const float*)d_in[10];
    const float* b2   = (const float*)d_in[11];
    const float* g1   = (const float*)d_in[12];
    const float* be1  = (const float*)d_in[13];
    const float* g2   = (const float*)d_in[14];
    const float* be2  = (const float*)d_in[15];
    float* out = (float*)d_out;

    char* w = (char*)d_ws;
    bf16_t* xb   = (bf16_t*)(w + 0);
    bf16_t* Wkvb = (bf16_t*)(w + 3276800);
    bf16_t* Wob  = (bf16_t*)(w + 4325376);
    bf16_t* W1b  = (bf16_t*)(w + 4849664);
    bf16_t* W2b  = (bf16_t*)(w + 6946816);
    bf16_t* Kb   = (bf16_t*)(w + 9043968);    // [128][200][64]
    bf16_t* Vt   = (bf16_t*)(w + 12320768);   // [128][64][256] zero-padded
    float*  posb = (float*)(w + 16515072);    // [200][200]
    float*  scal = (float*)(w + 16675072);
    bf16_t* vals = (bf16_t*)(w + 16675328);   // [3200][512] bf16
    float*  hf   = (float*)(w + 19952128);    // [3200][512] f32
    bf16_t* hb   = (bf16_t*)(w + 26505728);   // [3200][512] bf16
    char*   R    = w + 29782528;              // aliased region
    float*  scores = (float*)(R);             // [25600][208] f32 (21.3 MB)
    bf16_t* P    = (bf16_t*)(R + 21299200);   // [25600][256] bf16 (13.1 MB)
    bf16_t* tb   = (bf16_t*)(R);              // [3200][2048] bf16 (aliases scores)
    float*  obuf = (float*)(R + 13107200);    // 2 x [3200][512] f32 partials
    float*  fbuf = (float*)(R + 26214400);    // 4 x [3200][512] f32 partials

    const int M = B_ * S_;      // 3200
    const long PS = (long)M * D_;  // partial stride 1,638,400

    // 1) f32 -> bf16 converts
    convert_all<<<2048, 256, 0, stream>>>(x, Wkv, Wo, W1, W2, xb);
    // 2) zero Vt (K-padding for P@V)
    zero_f4<<<1024, 256, 0, stream>>>((float4*)Vt, 262144);
    // 3) positional bias + scale
    prep_posb<<<(S_ * S_ + 255) / 256, 256, 0, stream>>>(pos, Wpos, bpos, posb, scal);

    // 4) kv = x @ Wkv^T + bkv -> K bf16, V^T bf16 (400 blocks)
    mfma_gemm<64, 128, 32, 64, 3, 1><<<dim3(8, 50, 1), 256, 0, stream>>>(
        xb, 0, Wkvb, 0, nullptr, nullptr, 0, 0, bkv, nullptr, nullptr, Kb, Vt,
        M, 2 * D_, D_);

    // 5) scores = (K @ K^T)*scale + posb -> f32 (2048 blocks)
    mfma_gemm<64, 64, 32, 32, 2, 1><<<dim3(4, 4, 128), 256, 0, stream>>>(
        Kb, (long)S_ * HD_, Kb, (long)S_ * HD_, scores, nullptr, (long)S_ * 208, 208,
        nullptr, posb, scal, nullptr, nullptr, S_, S_, HD_);

    // 6) softmax rows -> bf16 P (zero-padded to 256)
    softmax_p<<<6400, 256, 0, stream>>>(scores, P);

    // 7) vals = P @ V -> bf16 (B,S,D)  (512 blocks)
    mfma_gemm<64, 64, 32, 32, 4, 1><<<dim3(1, 4, 128), 256, 0, stream>>>(
        P, (long)S_ * 256, Vt, (long)HD_ * 256, nullptr, vals, 0, D_,
        nullptr, nullptr, nullptr, nullptr, nullptr, S_, HD_, 256);

    // 8) o partials = vals @ Wo^T, split-K x2 (800 blocks)
    mfma_gemm<64, 64, 32, 32, 5, 2><<<dim3(8, 50, 2), 256, 0, stream>>>(
        vals, 0, Wob, 0, obuf, nullptr, PS, D_,
        nullptr, nullptr, nullptr, nullptr, nullptr, M, D_, D_);

    // 9) h = LN(x + o0 + o1 + bo) -> hf + hb
    add_ln_p<2><<<(M + 3) / 4, 256, 0, stream>>>(x, obuf, PS, bo, g1, be1, hf, hb, M);

    // 10) t = relu(h @ W1^T + b1) -> bf16 (800 blocks)
    mfma_gemm<64, 128, 32, 64, 1, 1><<<dim3(16, 50, 1), 256, 0, stream>>>(
        hb, 0, W1b, 0, nullptr, tb, 0, FF_, b1, nullptr, nullptr, nullptr, nullptr,
        M, FF_, D_);

    // 11) f partials = t @ W2^T, split-K x4 (1600 blocks)
    mfma_gemm<64, 64, 32, 32, 5, 4><<<dim3(8, 50, 4), 256, 0, stream>>>(
        tb, 0, W2b, 0, fbuf, nullptr, PS, D_,
        nullptr, nullptr, nullptr, nullptr, nullptr, M, D_, FF_);

    // 12) out = LN(h + f0..f3 + b2) -> f32
    add_ln_p<4><<<(M + 3) / 4, 256, 0, stream>>>(hf, fbuf, PS, b2, g2, be2, out, nullptr, M);
}

// Round 5
// 117.444 us; speedup vs baseline: 5.4545x; 1.1036x over previous
//
#include <hip/hip_runtime.h>
#include <hip/hip_bf16.h>

#define EPSV 1e-5f
static const int B_ = 16, S_ = 200, D_ = 512, H_ = 8, FF_ = 2048, P_ = 10, HD_ = 64;
static const int SP = 224;  // padded sequence length (14 x 16)

typedef __bf16 bf16_t;
typedef __attribute__((ext_vector_type(8))) __bf16 bf16x8;
typedef __attribute__((ext_vector_type(4))) __bf16 bf16x4;
typedef __attribute__((ext_vector_type(4))) float f32x4;

__device__ __forceinline__ void gload16(const void* g, void* l) {
    __builtin_amdgcn_global_load_lds(
        (const __attribute__((address_space(1))) void*)g,
        (__attribute__((address_space(3))) void*)l, 16, 0, 0);
}

// ---------------------------------------------------------------------------
// bf16 MFMA GEMM: C[M,N] = A[M,K] @ B[N,K]^T, 256 thr / 4 waves, BK=64.
// EPI: 1 = +bias,relu -> bf16 ; 3 = +bias, scatter K/Vt bf16 (strides SP) ;
//      5 = split-K partial -> f32 (no bias)
// ---------------------------------------------------------------------------
template <int BM, int BN, int WROWS, int WCOLS, int EPI, int NSPLIT>
__global__ __launch_bounds__(256) void mfma_gemm(
    const bf16_t* __restrict__ A,
    const bf16_t* __restrict__ Bw,
    float* __restrict__ Cf, bf16_t* __restrict__ Cb, long cBat, int ldc,
    const float* __restrict__ bias,
    bf16_t* __restrict__ kOut, bf16_t* __restrict__ vtOut,
    int M, int N, int K)
{
    constexpr int MR = WROWS / 16, NR = WCOLS / 16;
    constexpr int NWC = BN / WCOLS;
    static_assert((4 / NWC) * WROWS == BM, "wave tiling must cover BM");
    static_assert(NWC * WCOLS == BN, "wave tiling must cover BN");

    __shared__ bf16_t Asm[BM * 64];
    __shared__ bf16_t Bsm[BN * 64];

    const int wv = threadIdx.x >> 6;
    const int ln = threadIdx.x & 63;
    const int split = blockIdx.z % NSPLIT;
    const int rowBase = blockIdx.y * BM;
    const int colBase = blockIdx.x * BN;
    const int wr = (wv / NWC) * WROWS;
    const int wc = (wv % NWC) * WCOLS;

    const int lr8 = ln >> 3;
    const int lc = (ln & 7) * 8;

    f32x4 acc[MR][NR] = {};

    const int kBeg = split * (K / NSPLIT);
    const int kEnd = kBeg + K / NSPLIT;

    for (int k0 = kBeg; k0 < kEnd; k0 += 64) {
        #pragma unroll
        for (int i = 0; i < BM / 32; i++) {
            int row = i * 32 + wv * 8 + lr8;
            int gr = rowBase + row; gr = (gr < M) ? gr : (M - 1);
            gload16(A + (long)gr * K + k0 + lc, &Asm[(i * 32 + wv * 8) * 64]);
        }
        #pragma unroll
        for (int i = 0; i < BN / 32; i++) {
            int col = i * 32 + wv * 8 + lr8;
            int gc = colBase + col; gc = (gc < N) ? gc : (N - 1);
            gload16(Bw + (long)gc * K + k0 + lc, &Bsm[(i * 32 + wv * 8) * 64]);
        }
        __syncthreads();

        #pragma unroll
        for (int kk = 0; kk < 2; kk++) {
            bf16x8 af[MR], bfr[NR];
            #pragma unroll
            for (int m = 0; m < MR; m++)
                af[m] = *reinterpret_cast<const bf16x8*>(
                    &Asm[(wr + m * 16 + (ln & 15)) * 64 + kk * 32 + (ln >> 4) * 8]);
            #pragma unroll
            for (int n = 0; n < NR; n++)
                bfr[n] = *reinterpret_cast<const bf16x8*>(
                    &Bsm[(wc + n * 16 + (ln & 15)) * 64 + kk * 32 + (ln >> 4) * 8]);
            #pragma unroll
            for (int m = 0; m < MR; m++)
                #pragma unroll
                for (int n = 0; n < NR; n++)
                    acc[m][n] = __builtin_amdgcn_mfma_f32_16x16x32_bf16(
                        af[m], bfr[n], acc[m][n], 0, 0, 0);
        }
        __syncthreads();
    }

    #pragma unroll
    for (int m = 0; m < MR; m++) {
        #pragma unroll
        for (int n = 0; n < NR; n++) {
            #pragma unroll
            for (int r = 0; r < 4; r++) {
                int row = rowBase + wr + m * 16 + (ln >> 4) * 4 + r;
                int col = colBase + wc + n * 16 + (ln & 15);
                if (row >= M || col >= N) continue;
                float v = acc[m][n][r];
                if constexpr (EPI == 3) {
                    v += bias[col];
                    int b = row / S_, s = row - b * S_;
                    int h = col >> 7, w = col & 127;
                    if (w < HD_)
                        kOut[((long)(b * H_ + h) * SP + s) * HD_ + w] = (bf16_t)v;
                    else
                        vtOut[((long)(b * H_ + h) * HD_ + (w - HD_)) * SP + s] = (bf16_t)v;
                } else if constexpr (EPI == 1) {
                    v += bias[col];
                    v = fmaxf(v, 0.f);
                    Cb[(long)row * ldc + col] = (bf16_t)v;
                } else {  // 5
                    Cf[(long)split * cBat + (long)row * ldc + col] = v;
                }
            }
        }
    }
}

// ---------------------------------------------------------------------------
// Fused attention: scores = (Krows @ Kall^T)*scale + G[col]; softmax; @ V.
// Grid: (128 bh, 4 row-tiles). 4 waves x 16 rows. No __syncthreads needed.
// Kb: [bh][SP][64] bf16 (rows >= S zeroed); Vt: [bh][64][SP] bf16 (s >= S zeroed).
// ---------------------------------------------------------------------------
__global__ __launch_bounds__(256) void attn_fused(
    const bf16_t* __restrict__ Kb, const bf16_t* __restrict__ Vt,
    const float* __restrict__ G, const float* __restrict__ scalePtr,
    bf16_t* __restrict__ vals)
{
    __shared__ __align__(16) bf16_t Pl[4][16][232];

    const int bh = blockIdx.x;
    const int tile = blockIdx.y;
    const int wv = threadIdx.x >> 6;
    const int ln = threadIdx.x & 63;
    const int b = bh >> 3, h = bh & 7;
    const int rowBase = tile * 64 + wv * 16;

    const bf16_t* Kbh = Kb + (long)bh * SP * HD_;
    const bf16_t* Vbh = Vt + (long)bh * HD_ * SP;
    const float scale = scalePtr[0];

    const int lr = ln & 15;
    const int lk = (ln >> 4) * 8;

    // ---- phase 1: scores (14 col-frags, K = 64)
    f32x4 acc[14];
    #pragma unroll
    for (int n = 0; n < 14; n++) acc[n] = (f32x4){0.f, 0.f, 0.f, 0.f};

    int arow = rowBase + lr; arow = (arow < S_) ? arow : (S_ - 1);
    const bf16x8 a0 = *reinterpret_cast<const bf16x8*>(Kbh + (long)arow * HD_ + lk);
    const bf16x8 a1 = *reinterpret_cast<const bf16x8*>(Kbh + (long)arow * HD_ + 32 + lk);

    #pragma unroll
    for (int n = 0; n < 14; n++) {
        const bf16_t* bp = Kbh + (long)(n * 16 + lr) * HD_;
        bf16x8 b0 = *reinterpret_cast<const bf16x8*>(bp + lk);
        bf16x8 b1 = *reinterpret_cast<const bf16x8*>(bp + 32 + lk);
        acc[n] = __builtin_amdgcn_mfma_f32_16x16x32_bf16(a0, b0, acc[n], 0, 0, 0);
        acc[n] = __builtin_amdgcn_mfma_f32_16x16x32_bf16(a1, b1, acc[n], 0, 0, 0);
    }

    // ---- phase 2: softmax over 224 cols (4 rows/lane, 16-lane groups)
    float Gc[14];
    #pragma unroll
    for (int n = 0; n < 14; n++) Gc[n] = G[n * 16 + lr];

    #pragma unroll
    for (int r = 0; r < 4; r++) {
        float m = -1e30f;
        #pragma unroll
        for (int n = 0; n < 14; n++) {
            float v = acc[n][r] * scale + Gc[n];
            acc[n][r] = v;
            m = fmaxf(m, v);
        }
        #pragma unroll
        for (int off = 1; off < 16; off <<= 1) m = fmaxf(m, __shfl_xor(m, off));
        float s = 0.f;
        #pragma unroll
        for (int n = 0; n < 14; n++) {
            float e = __expf(acc[n][r] - m);
            acc[n][r] = e;
            s += e;
        }
        #pragma unroll
        for (int off = 1; off < 16; off <<= 1) s += __shfl_xor(s, off);
        float inv = 1.f / s;
        #pragma unroll
        for (int n = 0; n < 14; n++) acc[n][r] *= inv;
    }

    // ---- phase 3: P -> LDS (per-wave private; wave-internal ordering only)
    #pragma unroll
    for (int n = 0; n < 14; n++)
        #pragma unroll
        for (int r = 0; r < 4; r++)
            Pl[wv][(ln >> 4) * 4 + r][n * 16 + lr] = (bf16_t)acc[n][r];

    // ---- phase 4: PV (out 16 x 64, K = 224 = 7 x 32)
    f32x4 vacc[4] = {};
    #pragma unroll
    for (int kk = 0; kk < 7; kk++) {
        bf16x8 pa = *reinterpret_cast<const bf16x8*>(&Pl[wv][lr][kk * 32 + lk]);
        #pragma unroll
        for (int n = 0; n < 4; n++) {
            bf16x8 vb = *reinterpret_cast<const bf16x8*>(
                Vbh + (long)(n * 16 + lr) * SP + kk * 32 + lk);
            vacc[n] = __builtin_amdgcn_mfma_f32_16x16x32_bf16(pa, vb, vacc[n], 0, 0, 0);
        }
    }

    // ---- phase 5: write vals (B,S,D) bf16
    #pragma unroll
    for (int n = 0; n < 4; n++) {
        #pragma unroll
        for (int r = 0; r < 4; r++) {
            int row = rowBase + (ln >> 4) * 4 + r;
            if (row < S_)
                vals[((long)b * S_ + row) * D_ + h * HD_ + n * 16 + lr] =
                    (bf16_t)vacc[n][r];
        }
    }
}

// fused f32 -> bf16 conversion of x, Wkv, Wo, W1, W2 into one contiguous region
__global__ __launch_bounds__(256) void convert_all(
    const float* __restrict__ x, const float* __restrict__ Wkv,
    const float* __restrict__ Wo, const float* __restrict__ W1,
    const float* __restrict__ W2, bf16_t* __restrict__ dst)
{
    const int tot = 1130496;  // 4,521,984 / 4
    for (int i = blockIdx.x * blockDim.x + threadIdx.x; i < tot;
         i += gridDim.x * blockDim.x) {
        long e = (long)i * 4;
        const float* s; long off;
        if (e < 1638400)      { s = x;   off = e; }
        else if (e < 2162688) { s = Wkv; off = e - 1638400; }
        else if (e < 2424832) { s = Wo;  off = e - 2162688; }
        else if (e < 3473408) { s = W1;  off = e - 2424832; }
        else                  { s = W2;  off = e - 3473408; }
        float4 v = *reinterpret_cast<const float4*>(s + off);
        bf16x4 o = {(bf16_t)v.x, (bf16_t)v.y, (bf16_t)v.z, (bf16_t)v.w};
        *reinterpret_cast<bf16x4*>(dst + e) = o;
    }
}

__global__ __launch_bounds__(256) void zero_f4(float4* __restrict__ p, int n4)
{
    int i = blockIdx.x * blockDim.x + threadIdx.x;
    if (i < n4) p[i] = make_float4(0.f, 0.f, 0.f, 0.f);
}

// G[j] = sum_{p=6..9} pos[0][j][p]*Wpos[p]  (j < S), else -1e30 ; scale = sum(Wpos)/8
__global__ void prep_g(const float* __restrict__ pos, const float* __restrict__ Wpos,
                       float* __restrict__ G, float* __restrict__ scal)
{
    int t = threadIdx.x;
    if (t < SP) {
        float g = -1e30f;
        if (t < S_) {
            g = 0.f;
            #pragma unroll
            for (int p = 6; p < 10; p++) g += pos[(long)t * P_ + p] * Wpos[p];
        }
        G[t] = g;
    }
    if (t == 0) {
        float sw = 0.f;
        for (int p = 0; p < P_; p++) sw += Wpos[p];
        scal[0] = sw * 0.125f;
    }
}

// out = LayerNorm(a + sum_p parts[p] + bias); writes f32 outf, optional bf16 outb
template <int NPART>
__global__ __launch_bounds__(256) void add_ln_p(
    const float* __restrict__ a, const float* __restrict__ parts, long partStride,
    const float* __restrict__ bias,
    const float* __restrict__ g, const float* __restrict__ beta,
    float* __restrict__ outf, bf16_t* __restrict__ outb, int rows)
{
    int row = blockIdx.x * 4 + (threadIdx.x >> 6);
    int lane = threadIdx.x & 63;
    if (row >= rows) return;
    long base = (long)row * D_;
    float v[8];
    float sum = 0.f;
    #pragma unroll
    for (int i = 0; i < 8; i++) {
        int c = lane + i * 64;
        float t = a[base + c] + bias[c];
        #pragma unroll
        for (int p = 0; p < NPART; p++) t += parts[p * partStride + base + c];
        v[i] = t;
        sum += t;
    }
    #pragma unroll
    for (int off = 32; off; off >>= 1) sum += __shfl_xor(sum, off);
    float mean = sum * (1.f / 512.f);
    float var = 0.f;
    #pragma unroll
    for (int i = 0; i < 8; i++) { float d = v[i] - mean; var += d * d; }
    #pragma unroll
    for (int off = 32; off; off >>= 1) var += __shfl_xor(var, off);
    float rstd = rsqrtf(var * (1.f / 512.f) + EPSV);
    #pragma unroll
    for (int i = 0; i < 8; i++) {
        int c = lane + i * 64;
        float o = (v[i] - mean) * rstd * g[c] + beta[c];
        outf[base + c] = o;
        if (outb) outb[base + c] = (bf16_t)o;
    }
}

extern "C" void kernel_launch(void* const* d_in, const int* in_sizes, int n_in,
                              void* d_out, int out_size, void* d_ws, size_t ws_size,
                              hipStream_t stream)
{
    const float* x    = (const float*)d_in[0];
    const float* pos  = (const float*)d_in[1];
    const float* Wkv  = (const float*)d_in[2];
    const float* bkv  = (const float*)d_in[3];
    const float* Wo   = (const float*)d_in[4];
    const float* bo   = (const float*)d_in[5];
    const float* Wpos = (const float*)d_in[6];
    const float* bpos = (const float*)d_in[7];  // unused: softmax-invariant
    const float* W1   = (const float*)d_in[8];
    const float* b1   = (const float*)d_in[9];
    const float* W2   = (const float*)d_in[10];
    const float* b2   = (const float*)d_in[11];
    const float* g1   = (const float*)d_in[12];
    const float* be1  = (const float*)d_in[13];
    const float* g2   = (const float*)d_in[14];
    const float* be2  = (const float*)d_in[15];
    (void)bpos;
    float* out = (float*)d_out;

    char* w = (char*)d_ws;
    bf16_t* xb   = (bf16_t*)(w + 0);          // 3,276,800
    bf16_t* Wkvb = (bf16_t*)(w + 3276800);    // 1,048,576
    bf16_t* Wob  = (bf16_t*)(w + 4325376);    //   524,288
    bf16_t* W1b  = (bf16_t*)(w + 4849664);    // 2,097,152
    bf16_t* W2b  = (bf16_t*)(w + 6946816);    // 2,097,152
    bf16_t* Kb   = (bf16_t*)(w + 9043968);    // [128][224][64]  3,670,016
    bf16_t* Vt   = (bf16_t*)(w + 12713984);   // [128][64][224]  3,670,016
    float*  G    = (float*)(w + 16384000);    // [224]
    float*  scal = (float*)(w + 16384896);
    bf16_t* vals = (bf16_t*)(w + 16385024);   // [3200][512] bf16
    float*  hf   = (float*)(w + 19661824);    // [3200][512] f32
    bf16_t* hb   = (bf16_t*)(w + 26215424);   // [3200][512] bf16
    float*  obuf = (float*)(w + 29492224);    // 2 x [3200][512] f32
    bf16_t* tb   = (bf16_t*)(w + 42599424);   // [3200][2048] bf16
    float*  fbuf = (float*)(w + 55706624);    // 4 x [3200][512] f32 (ends ~82 MB)

    const int M = B_ * S_;        // 3200
    const long PS = (long)M * D_; // partial stride

    // 1) f32 -> bf16 converts
    convert_all<<<2048, 256, 0, stream>>>(x, Wkv, Wo, W1, W2, xb);
    // 2) zero Kb+Vt (contiguous 7,340,032 B) for the padded attention layouts
    zero_f4<<<1792, 256, 0, stream>>>((float4*)Kb, 458752);
    // 3) G vector + scale
    prep_g<<<1, 256, 0, stream>>>(pos, Wpos, G, scal);

    // 4) kv = x @ Wkv^T + bkv -> K [bh][224][64], V^T [bh][64][224] (400 blocks)
    mfma_gemm<64, 128, 32, 64, 3, 1><<<dim3(8, 50, 1), 256, 0, stream>>>(
        xb, Wkvb, nullptr, nullptr, 0, 0, bkv, Kb, Vt, M, 2 * D_, D_);

    // 5) fused attention -> vals bf16 (B,S,D)  (512 blocks)
    attn_fused<<<dim3(128, 4, 1), 256, 0, stream>>>(Kb, Vt, G, scal, vals);

    // 6) o partials = vals @ Wo^T, split-K x2 (800 blocks)
    mfma_gemm<64, 64, 32, 32, 5, 2><<<dim3(8, 50, 2), 256, 0, stream>>>(
        vals, Wob, obuf, nullptr, PS, D_, nullptr, nullptr, nullptr, M, D_, D_);

    // 7) h = LN(x + o0 + o1 + bo) -> hf + hb
    add_ln_p<2><<<(M + 3) / 4, 256, 0, stream>>>(x, obuf, PS, bo, g1, be1, hf, hb, M);

    // 8) t = relu(h @ W1^T + b1) -> bf16 (800 blocks)
    mfma_gemm<64, 128, 32, 64, 1, 1><<<dim3(16, 50, 1), 256, 0, stream>>>(
        hb, W1b, nullptr, tb, 0, FF_, b1, nullptr, nullptr, M, FF_, D_);

    // 9) f partials = t @ W2^T, split-K x4 (1600 blocks)
    mfma_gemm<64, 64, 32, 32, 5, 4><<<dim3(8, 50, 4), 256, 0, stream>>>(
        tb, W2b, fbuf, nullptr, PS, D_, nullptr, nullptr, nullptr, M, D_, FF_);

    // 10) out = LN(h + f0..f3 + b2) -> f32
    add_ln_p<4><<<(M + 3) / 4, 256, 0, stream>>>(hf, fbuf, PS, b2, g2, be2, out, nullptr, M);
}